// Round 1
// baseline (38.314 us; speedup 1.0000x reference)
//
#include <hip/hip_runtime.h>

// DEQ fixed-point: per row (B=8.4M, LATENT=3)
//   c   = W_in @ d_row + b_in + b_fc            (constant over iterations)
//   u_0 = 0;  u_{k+1} = relu(W_fc @ u_k + c)
//   stop at smallest k with max_i |u_k - u_{k+1}| < TOL  (per-row; contraction
//   makes this equivalent to the reference's global criterion within ~1e-3)
//   out = W_out @ u_{k+1} + b_out
//
// 4 rows per thread: d loads become 3x aligned float4 (48B), store 1x float4.

constexpr int ROWS_PER_THREAD = 4;

__global__ __launch_bounds__(256) void deq_fixed_point(
    const float* __restrict__ d,
    const float* __restrict__ W_fc,
    const float* __restrict__ b_fc,
    const float* __restrict__ W_in,
    const float* __restrict__ b_in,
    const float* __restrict__ W_out,
    const float* __restrict__ b_out,
    float* __restrict__ out,
    int nrows)
{
    const int t = blockIdx.x * blockDim.x + threadIdx.x;
    const long long base = (long long)t * ROWS_PER_THREAD;
    if (base >= nrows) return;

    // ---- uniform weights (L1-broadcast loads) ----
    const float wfc00 = W_fc[0], wfc01 = W_fc[1], wfc02 = W_fc[2];
    const float wfc10 = W_fc[3], wfc11 = W_fc[4], wfc12 = W_fc[5];
    const float wfc20 = W_fc[6], wfc21 = W_fc[7], wfc22 = W_fc[8];
    const float bfc0  = b_fc[0], bfc1  = b_fc[1], bfc2  = b_fc[2];
    const float win00 = W_in[0], win01 = W_in[1], win02 = W_in[2];
    const float win10 = W_in[3], win11 = W_in[4], win12 = W_in[5];
    const float win20 = W_in[6], win21 = W_in[7], win22 = W_in[8];
    const float bin0  = b_in[0], bin1  = b_in[1], bin2  = b_in[2];
    const float wo0   = W_out[0], wo1 = W_out[1], wo2 = W_out[2];
    const float bo    = b_out[0];

    // ---- load 4 rows of d (12 floats = 3 x float4, 16B-aligned) ----
    float dd[ROWS_PER_THREAD][3];
    if (base + ROWS_PER_THREAD <= (long long)nrows) {
        const float4* dp = reinterpret_cast<const float4*>(d + base * 3);
        const float4 v0 = dp[0], v1 = dp[1], v2 = dp[2];
        dd[0][0] = v0.x; dd[0][1] = v0.y; dd[0][2] = v0.z;
        dd[1][0] = v0.w; dd[1][1] = v1.x; dd[1][2] = v1.y;
        dd[2][0] = v1.z; dd[2][1] = v1.w; dd[2][2] = v2.x;
        dd[3][0] = v2.y; dd[3][1] = v2.z; dd[3][2] = v2.w;
    } else {
        for (int r = 0; r < ROWS_PER_THREAD; ++r) {
            const long long row = base + r;
            if (row < nrows) {
                dd[r][0] = d[row * 3 + 0];
                dd[r][1] = d[row * 3 + 1];
                dd[r][2] = d[row * 3 + 2];
            } else {
                dd[r][0] = dd[r][1] = dd[r][2] = 0.f;
            }
        }
    }

    float res[ROWS_PER_THREAD];
    #pragma unroll
    for (int r = 0; r < ROWS_PER_THREAD; ++r) {
        // c = W_in @ d + b_in + b_fc
        const float c0 = fmaf(win00, dd[r][0], fmaf(win01, dd[r][1], fmaf(win02, dd[r][2], bin0 + bfc0)));
        const float c1 = fmaf(win10, dd[r][0], fmaf(win11, dd[r][1], fmaf(win12, dd[r][2], bin1 + bfc1)));
        const float c2 = fmaf(win20, dd[r][0], fmaf(win21, dd[r][1], fmaf(win22, dd[r][2], bin2 + bfc2)));

        // carry: p = u_k, u = u_{k+1};  init p = u_0 = 0, u = u_1 = relu(c)
        float p0 = 0.f, p1 = 0.f, p2 = 0.f;
        float u0 = fmaxf(c0, 0.f);
        float u1 = fmaxf(c1, 0.f);
        float u2 = fmaxf(c2, 0.f);

        // reference: while (|u_k - u_{k+1}| >= TOL && i < 1000) advance;
        // output uses u_{k+1}.  Max 999 advances (i starts at 1).
        for (int it = 1; it < 1000; ++it) {
            const float diff = fmaxf(fmaxf(fabsf(u0 - p0), fabsf(u1 - p1)),
                                     fabsf(u2 - p2));
            if (diff < 1e-3f) break;
            p0 = u0; p1 = u1; p2 = u2;
            u0 = fmaxf(fmaf(wfc00, p0, fmaf(wfc01, p1, fmaf(wfc02, p2, c0))), 0.f);
            u1 = fmaxf(fmaf(wfc10, p0, fmaf(wfc11, p1, fmaf(wfc12, p2, c1))), 0.f);
            u2 = fmaxf(fmaf(wfc20, p0, fmaf(wfc21, p1, fmaf(wfc22, p2, c2))), 0.f);
        }

        // out = W_out @ u_{k+1} + b_out
        res[r] = fmaf(wo0, u0, fmaf(wo1, u1, fmaf(wo2, u2, bo)));
    }

    // ---- store 4 outputs as one float4 ----
    if (base + ROWS_PER_THREAD <= (long long)nrows) {
        float4 o;
        o.x = res[0]; o.y = res[1]; o.z = res[2]; o.w = res[3];
        *reinterpret_cast<float4*>(out + base) = o;
    } else {
        for (int r = 0; r < ROWS_PER_THREAD; ++r) {
            if (base + r < nrows) out[base + r] = res[r];
        }
    }
}

extern "C" void kernel_launch(void* const* d_in, const int* in_sizes, int n_in,
                              void* d_out, int out_size, void* d_ws, size_t ws_size,
                              hipStream_t stream) {
    const float* d     = (const float*)d_in[0];
    const float* W_fc  = (const float*)d_in[1];
    const float* b_fc  = (const float*)d_in[2];
    const float* W_in  = (const float*)d_in[3];
    const float* b_in  = (const float*)d_in[4];
    const float* W_out = (const float*)d_in[5];
    const float* b_out = (const float*)d_in[6];
    float* out = (float*)d_out;

    const int nrows = out_size;  // B (OUTPUT_DIM == 1)
    const int nthreads = (nrows + ROWS_PER_THREAD - 1) / ROWS_PER_THREAD;
    const int block = 256;
    const int grid = (nthreads + block - 1) / block;

    deq_fixed_point<<<grid, block, 0, stream>>>(
        d, W_fc, b_fc, W_in, b_in, W_out, b_out, out, nrows);
}

// Round 2
// 31.713 us; speedup vs baseline: 1.2081x; 1.2081x over previous
//
#include <hip/hip_runtime.h>

// DEQ fixed-point, per row (B=8.4M, LATENT=3):
//   c = W_in@d + b_in + b_fc;  u <- relu(W_fc@u + c) until |du|_inf < 1e-3; head.
// R1 restructure: 4 rows per thread iterated in LOCKSTEP (ILP), 6 unchecked
// iterations (no cmp/branch; typical convergence ~5-7), then checked
// ping-pong pairs (2 steps per check, no register copies). Extra iterations
// past the reference's stop point only converge further (contraction), which
// shrinks error vs the reference.

constexpr int RPT = 4;

__global__ __launch_bounds__(256) void deq_fixed_point(
    const float* __restrict__ d,
    const float* __restrict__ W_fc,
    const float* __restrict__ b_fc,
    const float* __restrict__ W_in,
    const float* __restrict__ b_in,
    const float* __restrict__ W_out,
    const float* __restrict__ b_out,
    float* __restrict__ out,
    int nrows)
{
    const int t = blockIdx.x * blockDim.x + threadIdx.x;
    const long long base = (long long)t * RPT;
    if (base >= nrows) return;

    // ---- uniform weights: thread-invariant addresses -> s_load (scalar pipe) ----
    const float w00 = W_fc[0], w01 = W_fc[1], w02 = W_fc[2];
    const float w10 = W_fc[3], w11 = W_fc[4], w12 = W_fc[5];
    const float w20 = W_fc[6], w21 = W_fc[7], w22 = W_fc[8];
    const float bf0 = b_fc[0], bf1 = b_fc[1], bf2 = b_fc[2];
    const float i00 = W_in[0], i01 = W_in[1], i02 = W_in[2];
    const float i10 = W_in[3], i11 = W_in[4], i12 = W_in[5];
    const float i20 = W_in[6], i21 = W_in[7], i22 = W_in[8];
    const float bi0 = b_in[0], bi1 = b_in[1], bi2 = b_in[2];
    const float o0  = W_out[0], o1 = W_out[1], o2 = W_out[2];
    const float ob  = b_out[0];

    // ---- load 4 rows of d (12 floats = 3 x float4) ----
    float dd[RPT][3];
    if (base + RPT <= (long long)nrows) {
        const float4* dp = reinterpret_cast<const float4*>(d + base * 3);
        const float4 v0 = dp[0], v1 = dp[1], v2 = dp[2];
        dd[0][0] = v0.x; dd[0][1] = v0.y; dd[0][2] = v0.z;
        dd[1][0] = v0.w; dd[1][1] = v1.x; dd[1][2] = v1.y;
        dd[2][0] = v1.z; dd[2][1] = v1.w; dd[2][2] = v2.x;
        dd[3][0] = v2.y; dd[3][1] = v2.z; dd[3][2] = v2.w;
    } else {
        for (int r = 0; r < RPT; ++r) {
            const long long row = base + r;
            if (row < nrows) {
                dd[r][0] = d[row * 3 + 0];
                dd[r][1] = d[row * 3 + 1];
                dd[r][2] = d[row * 3 + 2];
            } else {
                dd[r][0] = dd[r][1] = dd[r][2] = 0.f;
            }
        }
    }

    // ---- c = W_in@d + b_in + b_fc;  u = T(0) = relu(c) ----
    float c[RPT][3], u[RPT][3];
    #pragma unroll
    for (int r = 0; r < RPT; ++r) {
        c[r][0] = fmaf(i00, dd[r][0], fmaf(i01, dd[r][1], fmaf(i02, dd[r][2], bi0 + bf0)));
        c[r][1] = fmaf(i10, dd[r][0], fmaf(i11, dd[r][1], fmaf(i12, dd[r][2], bi1 + bf1)));
        c[r][2] = fmaf(i20, dd[r][0], fmaf(i21, dd[r][1], fmaf(i22, dd[r][2], bi2 + bf2)));
        u[r][0] = fmaxf(c[r][0], 0.f);
        u[r][1] = fmaxf(c[r][1], 0.f);
        u[r][2] = fmaxf(c[r][2], 0.f);
    }

    // ---- 6 unchecked iterations, rows interleaved (pure FMA+max, full ILP) ----
    #pragma unroll
    for (int it = 0; it < 6; ++it) {
        #pragma unroll
        for (int r = 0; r < RPT; ++r) {
            const float a0 = fmaxf(fmaf(w00, u[r][0], fmaf(w01, u[r][1], fmaf(w02, u[r][2], c[r][0]))), 0.f);
            const float a1 = fmaxf(fmaf(w10, u[r][0], fmaf(w11, u[r][1], fmaf(w12, u[r][2], c[r][1]))), 0.f);
            const float a2 = fmaxf(fmaf(w20, u[r][0], fmaf(w21, u[r][1], fmaf(w22, u[r][2], c[r][2]))), 0.f);
            u[r][0] = a0; u[r][1] = a1; u[r][2] = a2;
        }
    }

    // ---- checked ping-pong pairs: v = T(u); u = T(v); stop when |u-v| < tol.
    // Stopping index is always >= the reference's per-row stop (diffs shrink
    // monotonically under contraction), so we only ever over-converge.
    for (int pair = 0; pair < 500; ++pair) {
        float v[RPT][3];
        #pragma unroll
        for (int r = 0; r < RPT; ++r) {
            v[r][0] = fmaxf(fmaf(w00, u[r][0], fmaf(w01, u[r][1], fmaf(w02, u[r][2], c[r][0]))), 0.f);
            v[r][1] = fmaxf(fmaf(w10, u[r][0], fmaf(w11, u[r][1], fmaf(w12, u[r][2], c[r][1]))), 0.f);
            v[r][2] = fmaxf(fmaf(w20, u[r][0], fmaf(w21, u[r][1], fmaf(w22, u[r][2], c[r][2]))), 0.f);
        }
        float diff = 0.f;
        #pragma unroll
        for (int r = 0; r < RPT; ++r) {
            const float a0 = fmaxf(fmaf(w00, v[r][0], fmaf(w01, v[r][1], fmaf(w02, v[r][2], c[r][0]))), 0.f);
            const float a1 = fmaxf(fmaf(w10, v[r][0], fmaf(w11, v[r][1], fmaf(w12, v[r][2], c[r][1]))), 0.f);
            const float a2 = fmaxf(fmaf(w20, v[r][0], fmaf(w21, v[r][1], fmaf(w22, v[r][2], c[r][2]))), 0.f);
            diff = fmaxf(diff, fabsf(a0 - v[r][0]));
            diff = fmaxf(diff, fabsf(a1 - v[r][1]));
            diff = fmaxf(diff, fabsf(a2 - v[r][2]));
            u[r][0] = a0; u[r][1] = a1; u[r][2] = a2;
        }
        if (diff < 1e-3f) break;
    }

    // ---- output head + float4 store ----
    float res[RPT];
    #pragma unroll
    for (int r = 0; r < RPT; ++r)
        res[r] = fmaf(o0, u[r][0], fmaf(o1, u[r][1], fmaf(o2, u[r][2], ob)));

    if (base + RPT <= (long long)nrows) {
        float4 o;
        o.x = res[0]; o.y = res[1]; o.z = res[2]; o.w = res[3];
        *reinterpret_cast<float4*>(out + base) = o;
    } else {
        for (int r = 0; r < RPT; ++r)
            if (base + r < nrows) out[base + r] = res[r];
    }
}

extern "C" void kernel_launch(void* const* d_in, const int* in_sizes, int n_in,
                              void* d_out, int out_size, void* d_ws, size_t ws_size,
                              hipStream_t stream) {
    const float* d     = (const float*)d_in[0];
    const float* W_fc  = (const float*)d_in[1];
    const float* b_fc  = (const float*)d_in[2];
    const float* W_in  = (const float*)d_in[3];
    const float* b_in  = (const float*)d_in[4];
    const float* W_out = (const float*)d_in[5];
    const float* b_out = (const float*)d_in[6];
    float* out = (float*)d_out;

    const int nrows = out_size;  // B (OUTPUT_DIM == 1)
    const int nthreads = (nrows + RPT - 1) / RPT;
    const int block = 256;
    const int grid = (nthreads + block - 1) / block;

    deq_fixed_point<<<grid, block, 0, stream>>>(
        d, W_fc, b_fc, W_in, b_in, W_out, b_out, out, nrows);
}